// Round 4
// baseline (1097.949 us; speedup 1.0000x reference)
//
#include <hip/hip_runtime.h>

#define BB 4
#define SS 2048
#define DDIM 512
#define HH 8
#define MTOK (BB*SS)   // 8192
#define BHN (BB*HH)    // 32

typedef _Float16 f16;
typedef __attribute__((ext_vector_type(8))) _Float16 half8;
typedef __attribute__((ext_vector_type(4))) _Float16 half4;
typedef __attribute__((ext_vector_type(4))) float float4v;
typedef __attribute__((ext_vector_type(4))) int int4v;

#define SCALE_L2E 0.180336880073616f   // 0.125 * log2(e)
#define L2E 1.44269504088896f

__device__ __forceinline__ float4v mfma16(half8 a, half8 b, float4v c) {
  return __builtin_amdgcn_mfma_f32_16x16x32_f16(a, b, c, 0, 0, 0);
}

__device__ __forceinline__ half8 cvt8(float4v a, float4v b) {
  half8 r;
  r[0] = (f16)a[0]; r[1] = (f16)a[1]; r[2] = (f16)a[2]; r[3] = (f16)a[3];
  r[4] = (f16)b[0]; r[5] = (f16)b[1]; r[6] = (f16)b[2]; r[7] = (f16)b[3];
  return r;
}

// ---------------- mask dtype detection ----------------
__global__ __launch_bounds__(256) void detect_mask_kernel(
    const unsigned int* __restrict__ m, unsigned int* __restrict__ flag) {
  unsigned int v = 0;
  for (int j = threadIdx.x; j < 65536; j += 256)
    if (m[j] > 1u) v = 1u;
  if (v) atomicOr(flag, 1u);
}

// ---------------- GEMM: [8192,512] x [512,512]^T ----------------
// AMODE 0: A fp32 [tok][512].  AMODE 1: A = ctx2 halves f16 (sum while staging).
// OUTMODE 0: f32 [tok][512]; 1: f16 [tok][512]; 2: Kpk [bh][tok][64];
// 3: Vtt [bh][dv][tok].
template<int AMODE, int OUTMODE>
__global__ __launch_bounds__(256) void gemm512(const void* __restrict__ Ain,
                                               const float* __restrict__ W,
                                               void* __restrict__ Outv) {
  __shared__ f16 As[128][40];
  __shared__ f16 Bs[128][40];
  const int t = threadIdx.x;
  const int bm = blockIdx.x * 128;
  const int bn = blockIdx.y * 128;
  const int w = t >> 6, ln = t & 63;
  const int wr = w >> 1, wc = w & 1;
  const int lr = ln & 15, lg = ln >> 4;
  const int srow = t >> 1, scol = (t & 1) * 16;

  float4v acc[4][4] = {};

  for (int k0 = 0; k0 < 512; k0 += 32) {
    if (AMODE == 1) {
      const f16* ap = (const f16*)Ain + (size_t)(bm + srow) * 512 + k0 + scol;
      const f16* ap2 = ap + (size_t)MTOK * 512;
      half8 x0 = *(const half8*)(ap),      x1 = *(const half8*)(ap + 8);
      half8 y0 = *(const half8*)(ap2),     y1 = *(const half8*)(ap2 + 8);
      *(half8*)&As[srow][scol]     = x0 + y0;
      *(half8*)&As[srow][scol + 8] = x1 + y1;
    } else {
      const float* ap = (const float*)Ain + (size_t)(bm + srow) * 512 + k0 + scol;
      float4v x0 = *(const float4v*)ap,       x1 = *(const float4v*)(ap + 4);
      float4v x2 = *(const float4v*)(ap + 8), x3 = *(const float4v*)(ap + 12);
      *(half8*)&As[srow][scol]     = cvt8(x0, x1);
      *(half8*)&As[srow][scol + 8] = cvt8(x2, x3);
    }
    {
      const float* wp = W + (size_t)(bn + srow) * 512 + k0 + scol;
      float4v x0 = *(const float4v*)wp,       x1 = *(const float4v*)(wp + 4);
      float4v x2 = *(const float4v*)(wp + 8), x3 = *(const float4v*)(wp + 12);
      *(half8*)&Bs[srow][scol]     = cvt8(x0, x1);
      *(half8*)&Bs[srow][scol + 8] = cvt8(x2, x3);
    }
    __syncthreads();
    half8 af[4], bf[4];
    #pragma unroll
    for (int m = 0; m < 4; m++) af[m] = *(const half8*)&As[wr * 64 + m * 16 + lr][lg * 8];
    #pragma unroll
    for (int n = 0; n < 4; n++) bf[n] = *(const half8*)&Bs[wc * 64 + n * 16 + lr][lg * 8];
    #pragma unroll
    for (int m = 0; m < 4; m++)
      #pragma unroll
      for (int n = 0; n < 4; n++) acc[m][n] = mfma16(af[m], bf[n], acc[m][n]);
    __syncthreads();
  }

  #pragma unroll
  for (int m = 0; m < 4; m++) {
    int row = bm + wr * 64 + m * 16 + lg * 4;
    #pragma unroll
    for (int n = 0; n < 4; n++) {
      int col = bn + wc * 64 + n * 16 + lr;
      if (OUTMODE == 0) {
        #pragma unroll
        for (int r = 0; r < 4; r++)
          ((float*)Outv)[(size_t)(row + r) * 512 + col] = acc[m][n][r];
      } else if (OUTMODE == 1) {
        #pragma unroll
        for (int r = 0; r < 4; r++)
          ((f16*)Outv)[(size_t)(row + r) * 512 + col] = (f16)acc[m][n][r];
      } else if (OUTMODE == 2) {
        // Kpk[bh][tok][64]
        int b_ = row >> 11, s_ = row & 2047, h_ = col >> 6, dk_ = col & 63;
        #pragma unroll
        for (int r = 0; r < 4; r++)
          ((f16*)Outv)[(((size_t)(b_ * 8 + h_)) * SS + s_ + r) * 64 + dk_] =
              (f16)acc[m][n][r];
      } else {
        // Vtt[bh][dv][tok] - 4 consecutive tok -> half4 store
        int b_ = row >> 11, s_ = row & 2047, h_ = col >> 6, dv_ = col & 63;
        half4 ph;
        ph[0] = (f16)acc[m][n][0]; ph[1] = (f16)acc[m][n][1];
        ph[2] = (f16)acc[m][n][2]; ph[3] = (f16)acc[m][n][3];
        *(half4*)&((f16*)Outv)[(((size_t)(b_ * 8 + h_)) * 64 + dv_) * SS + s_] = ph;
      }
    }
  }
}

// ---------------- fused attention, direct-from-L2 operands ----------------
// Block = (b, kh, 16 q-rows). grid 1024; bid&7 = (b,kh) = XCD id so each
// XCD's L2 holds one K+V slice (~2 MB). No K/V/other LDS staging (K rows are
// wave-disjoint in the S^T layout; other/mask are L2-hot across the 8-head
// inner loop). Only P goes through LDS (layout shuffle for PV), double
// buffered -> ONE barrier per (kt,h). 4 blocks/CU resident.
template<int PHASE>
__global__ __launch_bounds__(256, 4) void attn_fused(
    const f16* __restrict__ Qp, const f16* __restrict__ Kpk,
    const f16* __restrict__ Vtt, const float* __restrict__ other,
    const unsigned char* __restrict__ mask8, const int* __restrict__ mask32,
    const unsigned int* __restrict__ flag, float* __restrict__ lsum2,
    float* __restrict__ attn_out, f16* __restrict__ ctx2) {
  constexpr int SMEM = (PHASE == 1) ? 2048 : 2 * 16 * 136 * 2;
  __shared__ char smem_raw[SMEM];
  f16* Ps = (f16*)smem_raw;            // [2][16][136] (PHASE2)
  float* red = (float*)smem_raw;       // [4][8][16]   (PHASE1)

  const int t = threadIdx.x;
  const int bid = blockIdx.x;
  const int b  = (bid & 7) >> 1;
  const int kh = bid & 1;
  const int qblk = (bid >> 3) * 16;
  const int w = t >> 6, ln = t & 63;
  const int lr = ln & 15, lg = ln >> 4;
  const bool use8 = (*flag) != 0;

  float invl[8];
  if (PHASE == 2) {
    #pragma unroll
    for (int h = 0; h < 8; h++) {
      size_t qi = (size_t)(b * 8 + h) * SS + qblk + lr;
      invl[h] = 1.0f / (lsum2[qi] + lsum2[(size_t)BHN * SS + qi]);
    }
  }

  float rs[8];
  float4v cacc[8] = {};
  #pragma unroll
  for (int h = 0; h < 8; h++) rs[h] = 0.f;

  const int kt0 = kh * 1024;
  for (int kti = 0; kti < 8; kti++) {
    const int kb = kt0 + kti * 128;
    #pragma unroll
    for (int h = 0; h < 8; h++) {
      const int p = h & 1;  // Ps double-buffer (8 heads -> continuous toggle)
      // Q fragments (L2-hot)
      const f16* qbase = Qp + ((size_t)b * SS + qblk + lr) * 512 + h * 64 + lg * 8;
      half8 qf[2];
      qf[0] = *(const half8*)(qbase);
      qf[1] = *(const half8*)(qbase + 32);
      // K fragments direct (wave-disjoint rows)
      const f16* kbase = Kpk + ((size_t)(b * 8 + h) * SS + kb + w * 32 + lr) * 64 + lg * 8;
      half8 kf[2][2];
      #pragma unroll
      for (int n = 0; n < 2; n++)
        #pragma unroll
        for (int ks = 0; ks < 2; ks++)
          kf[n][ks] = *(const half8*)(kbase + n * 1024 + ks * 32);
      // V fragments direct (PHASE2)
      half8 vf[4];
      if (PHASE == 2) {
        const f16* vbase = Vtt + ((size_t)(b * 8 + h) * 64 + w * 16 + lr) * SS + kb + lg * 8;
        #pragma unroll
        for (int ks = 0; ks < 4; ks++) vf[ks] = *(const half8*)(vbase + ks * 32);
      }
      // QK^T transposed: row = k-token, col = q
      float4v sacc[2] = {};
      #pragma unroll
      for (int ks = 0; ks < 2; ks++) {
        sacc[0] = mfma16(kf[0][ks], qf[ks], sacc[0]);
        sacc[1] = mfma16(kf[1][ks], qf[ks], sacc[1]);
      }
      // epilogue: bias + mask + exp (+ normalize/store)
      #pragma unroll
      for (int n = 0; n < 2; n++) {
        const int kc = w * 32 + n * 16 + lg * 4;
        const size_t obase = ((size_t)b * SS + qblk + lr) * SS + kb + kc;
        float4v oth = *(const float4v*)&other[obase];
        unsigned int mwb = 0;
        int4v mw4;
        if (use8) mwb = *(const unsigned int*)&mask8[obase];
        else      mw4 = *(const int4v*)&mask32[obase];
        float4v ev;
        #pragma unroll
        for (int r = 0; r < 4; r++) {
          bool mk = use8 ? (((mwb >> (8 * r)) & 0xffu) != 0u) : (mw4[r] != 0);
          float o2 = mk ? -1e9f : oth[r] * L2E;
          ev[r] = exp2f(fmaf(sacc[n][r], SCALE_L2E, o2));
        }
        if (PHASE == 1) {
          rs[h] += (ev[0] + ev[1]) + (ev[2] + ev[3]);
        } else {
          float4v av = ev * invl[h];
          __builtin_nontemporal_store(
              av, (float4v*)&attn_out[((size_t)(b * 8 + h) * SS + qblk + lr) * SS + kb + kc]);
          half4 ph;
          ph[0] = (f16)av[0]; ph[1] = (f16)av[1];
          ph[2] = (f16)av[2]; ph[3] = (f16)av[3];
          *(half4*)&Ps[(p * 16 * 136) + lr * 136 + kc] = ph;
        }
      }
      if (PHASE == 2) {
        __syncthreads();  // Ps[p] complete (single barrier per (kt,h))
        #pragma unroll
        for (int ks = 0; ks < 4; ks++) {
          half8 pf = *(const half8*)&Ps[(p * 16 * 136) + lr * 136 + ks * 32 + lg * 8];
          cacc[h] = mfma16(pf, vf[ks], cacc[h]);
        }
      }
    }
  }

  if (PHASE == 1) {
    #pragma unroll
    for (int h = 0; h < 8; h++) {
      float v = rs[h];
      v += __shfl_xor(v, 16);
      v += __shfl_xor(v, 32);
      if (ln < 16) red[(w * 8 + h) * 16 + lr] = v;
    }
    __syncthreads();
    if (t < 128) {
      const int h = t >> 4, q = t & 15;
      float tot = red[(0 + h) * 16 + q] + red[(8 + h) * 16 + q] +
                  red[(16 + h) * 16 + q] + red[(24 + h) * 16 + q];
      lsum2[(size_t)kh * BHN * SS + (size_t)(b * 8 + h) * SS + qblk + q] = tot;
    }
  } else {
    #pragma unroll
    for (int h = 0; h < 8; h++) {
      #pragma unroll
      for (int r = 0; r < 4; r++) {
        ctx2[(size_t)kh * MTOK * 512 +
             ((size_t)b * SS + qblk + lg * 4 + r) * 512 +
             h * 64 + w * 16 + lr] = (f16)cacc[h][r];
      }
    }
  }
}

extern "C" void kernel_launch(void* const* d_in, const int* in_sizes, int n_in,
                              void* d_out, int out_size, void* d_ws, size_t ws_size,
                              hipStream_t stream) {
  const float* inQ   = (const float*)d_in[0];
  const float* inK   = (const float*)d_in[1];
  const float* inV   = (const float*)d_in[2];
  const void*  mask  = d_in[3];
  const float* other = (const float*)d_in[4];
  const float* WQ    = (const float*)d_in[5];
  const float* WK    = (const float*)d_in[6];
  const float* WV    = (const float*)d_in[7];
  const float* WF    = (const float*)d_in[8];

  char* ws = (char*)d_ws;
  size_t off = 0;
  unsigned int* flag = (unsigned int*)(ws + off); off += 256;
  f16* Qp    = (f16*)(ws + off); off += (size_t)MTOK * 512 * 2;
  f16* Kpk   = (f16*)(ws + off); off += (size_t)MTOK * 512 * 2;
  f16* Vtt   = (f16*)(ws + off); off += (size_t)MTOK * 512 * 2;
  float* lsum2 = (float*)(ws + off); off += (size_t)2 * BHN * SS * 4;
  f16* ctx2  = (f16*)(ws + off); off += (size_t)2 * MTOK * 512 * 2;
  if (ws_size < off) return;

  float* outp  = (float*)d_out;
  float* attnp = outp + (size_t)MTOK * DDIM;

  hipMemsetAsync(flag, 0, 256, stream);
  detect_mask_kernel<<<1, 256, 0, stream>>>((const unsigned int*)mask, flag);

  dim3 pg(64, 4);
  gemm512<0, 1><<<pg, 256, 0, stream>>>(inQ, WQ, Qp);
  gemm512<0, 2><<<pg, 256, 0, stream>>>(inK, WK, Kpk);
  gemm512<0, 3><<<pg, 256, 0, stream>>>(inV, WV, Vtt);

  attn_fused<1><<<1024, 256, 0, stream>>>(
      Qp, Kpk, Vtt, other, (const unsigned char*)mask, (const int*)mask, flag,
      lsum2, attnp, ctx2);
  attn_fused<2><<<1024, 256, 0, stream>>>(
      Qp, Kpk, Vtt, other, (const unsigned char*)mask, (const int*)mask, flag,
      lsum2, attnp, ctx2);

  gemm512<1, 0><<<pg, 256, 0, stream>>>(ctx2, WF, outp);
}

// Round 5
// 587.136 us; speedup vs baseline: 1.8700x; 1.8700x over previous
//
#include <hip/hip_runtime.h>

#define BB 4
#define SS 2048
#define DDIM 512
#define HH 8
#define MTOK (BB*SS)   // 8192
#define BHN (BB*HH)    // 32

typedef _Float16 f16;
typedef __attribute__((ext_vector_type(8))) _Float16 half8;
typedef __attribute__((ext_vector_type(4))) _Float16 half4;
typedef __attribute__((ext_vector_type(4))) float float4v;
typedef __attribute__((ext_vector_type(4))) int int4v;
typedef __attribute__((ext_vector_type(4))) unsigned int uint4v;

#define SCALE_L2E 0.180336880073616f   // 0.125 * log2(e)
#define L2E 1.44269504088896f

__device__ __forceinline__ float4v mfma16(half8 a, half8 b, float4v c) {
  return __builtin_amdgcn_mfma_f32_16x16x32_f16(a, b, c, 0, 0, 0);
}

__device__ __forceinline__ half8 cvt8(float4v a, float4v b) {
  half8 r;
  r[0] = (f16)a[0]; r[1] = (f16)a[1]; r[2] = (f16)a[2]; r[3] = (f16)a[3];
  r[4] = (f16)b[0]; r[5] = (f16)b[1]; r[6] = (f16)b[2]; r[7] = (f16)b[3];
  return r;
}

// ---------------- mask dtype detection ----------------
__global__ __launch_bounds__(256) void detect_mask_kernel(
    const unsigned int* __restrict__ m, unsigned int* __restrict__ flag) {
  unsigned int v = 0;
  for (int j = threadIdx.x; j < 65536; j += 256)
    if (m[j] > 1u) v = 1u;
  if (v) atomicOr(flag, 1u);
}

// ---------------- batched QKV projection: z selects (input, W, layout) ----------------
// Out[m,n] = sum_k A[m,k] * W[n,k].  z=0: Qp [tok][512] f16; z=1: Kpk
// [bh][tok][64]; z=2: Vtt [bh][dv][tok].
__global__ __launch_bounds__(256) void gemm_qkv(
    const float* __restrict__ inQ, const float* __restrict__ inK,
    const float* __restrict__ inV, const float* __restrict__ WQ,
    const float* __restrict__ WK, const float* __restrict__ WV,
    f16* __restrict__ Qp, f16* __restrict__ Kpk, f16* __restrict__ Vtt) {
  __shared__ f16 As[128][40];
  __shared__ f16 Bs[128][40];
  const int z = blockIdx.z;
  const float* A = (z == 0) ? inQ : (z == 1) ? inK : inV;
  const float* W = (z == 0) ? WQ : (z == 1) ? WK : WV;
  const int t = threadIdx.x;
  const int bm = blockIdx.x * 128;
  const int bn = blockIdx.y * 128;
  const int w = t >> 6, ln = t & 63;
  const int wr = w >> 1, wc = w & 1;
  const int lr = ln & 15, lg = ln >> 4;
  const int srow = t >> 1, scol = (t & 1) * 16;

  float4v acc[4][4] = {};

  for (int k0 = 0; k0 < 512; k0 += 32) {
    {
      const float* ap = A + (size_t)(bm + srow) * 512 + k0 + scol;
      float4v x0 = *(const float4v*)ap,       x1 = *(const float4v*)(ap + 4);
      float4v x2 = *(const float4v*)(ap + 8), x3 = *(const float4v*)(ap + 12);
      *(half8*)&As[srow][scol]     = cvt8(x0, x1);
      *(half8*)&As[srow][scol + 8] = cvt8(x2, x3);
    }
    {
      const float* wp = W + (size_t)(bn + srow) * 512 + k0 + scol;
      float4v x0 = *(const float4v*)wp,       x1 = *(const float4v*)(wp + 4);
      float4v x2 = *(const float4v*)(wp + 8), x3 = *(const float4v*)(wp + 12);
      *(half8*)&Bs[srow][scol]     = cvt8(x0, x1);
      *(half8*)&Bs[srow][scol + 8] = cvt8(x2, x3);
    }
    __syncthreads();
    half8 af[4], bf[4];
    #pragma unroll
    for (int m = 0; m < 4; m++) af[m] = *(const half8*)&As[wr * 64 + m * 16 + lr][lg * 8];
    #pragma unroll
    for (int n = 0; n < 4; n++) bf[n] = *(const half8*)&Bs[wc * 64 + n * 16 + lr][lg * 8];
    #pragma unroll
    for (int m = 0; m < 4; m++)
      #pragma unroll
      for (int n = 0; n < 4; n++) acc[m][n] = mfma16(af[m], bf[n], acc[m][n]);
    __syncthreads();
  }

  #pragma unroll
  for (int m = 0; m < 4; m++) {
    int row = bm + wr * 64 + m * 16 + lg * 4;
    #pragma unroll
    for (int n = 0; n < 4; n++) {
      int col = bn + wc * 64 + n * 16 + lr;
      int b_ = row >> 11, s_ = row & 2047, h_ = col >> 6, d_ = col & 63;
      if (z == 0) {
        #pragma unroll
        for (int r = 0; r < 4; r++)
          Qp[(size_t)(row + r) * 512 + col] = (f16)acc[m][n][r];
      } else if (z == 1) {
        #pragma unroll
        for (int r = 0; r < 4; r++)
          Kpk[(((size_t)(b_ * 8 + h_)) * SS + s_ + r) * 64 + d_] = (f16)acc[m][n][r];
      } else {
        half4 ph;
        ph[0] = (f16)acc[m][n][0]; ph[1] = (f16)acc[m][n][1];
        ph[2] = (f16)acc[m][n][2]; ph[3] = (f16)acc[m][n][3];
        *(half4*)&Vtt[(((size_t)(b_ * 8 + h_)) * 64 + d_) * SS + s_] = ph;
      }
    }
  }
}

// ---------------- final output GEMM: ctx2 halves summed, fp32 out ----------------
__global__ __launch_bounds__(256) void gemm_out(const f16* __restrict__ ctx2,
                                                const float* __restrict__ W,
                                                float* __restrict__ Out) {
  __shared__ f16 As[128][40];
  __shared__ f16 Bs[128][40];
  const int t = threadIdx.x;
  const int bm = blockIdx.x * 128;
  const int bn = blockIdx.y * 128;
  const int w = t >> 6, ln = t & 63;
  const int wr = w >> 1, wc = w & 1;
  const int lr = ln & 15, lg = ln >> 4;
  const int srow = t >> 1, scol = (t & 1) * 16;

  float4v acc[4][4] = {};

  for (int k0 = 0; k0 < 512; k0 += 32) {
    {
      const f16* ap = ctx2 + (size_t)(bm + srow) * 512 + k0 + scol;
      const f16* ap2 = ap + (size_t)MTOK * 512;
      half8 x0 = *(const half8*)(ap),  x1 = *(const half8*)(ap + 8);
      half8 y0 = *(const half8*)(ap2), y1 = *(const half8*)(ap2 + 8);
      *(half8*)&As[srow][scol]     = x0 + y0;
      *(half8*)&As[srow][scol + 8] = x1 + y1;
    }
    {
      const float* wp = W + (size_t)(bn + srow) * 512 + k0 + scol;
      float4v x0 = *(const float4v*)wp,       x1 = *(const float4v*)(wp + 4);
      float4v x2 = *(const float4v*)(wp + 8), x3 = *(const float4v*)(wp + 12);
      *(half8*)&Bs[srow][scol]     = cvt8(x0, x1);
      *(half8*)&Bs[srow][scol + 8] = cvt8(x2, x3);
    }
    __syncthreads();
    half8 af[4], bf[4];
    #pragma unroll
    for (int m = 0; m < 4; m++) af[m] = *(const half8*)&As[wr * 64 + m * 16 + lr][lg * 8];
    #pragma unroll
    for (int n = 0; n < 4; n++) bf[n] = *(const half8*)&Bs[wc * 64 + n * 16 + lr][lg * 8];
    #pragma unroll
    for (int m = 0; m < 4; m++)
      #pragma unroll
      for (int n = 0; n < 4; n++) acc[m][n] = mfma16(af[m], bf[n], acc[m][n]);
    __syncthreads();
  }

  #pragma unroll
  for (int m = 0; m < 4; m++) {
    int row = bm + wr * 64 + m * 16 + lg * 4;
    #pragma unroll
    for (int n = 0; n < 4; n++) {
      int col = bn + wc * 64 + n * 16 + lr;
      #pragma unroll
      for (int r = 0; r < 4; r++)
        Out[(size_t)(row + r) * 512 + col] = acc[m][n][r];
    }
  }
}

// ---------------- fused attention ----------------
// Block = (b, kh, qblk 32 rows [, h-half in PHASE2]).  bid&7 = (b,kh) -> XCD.
// other+mask staged ONCE per kt into LDS (log2e-scaled, -1e9 masked), reused
// by all NH heads.  K/V/Q read direct from global (L2-hot; K rows are
// wave-disjoint in the S^T layout so LDS staging buys nothing).  Only P goes
// through LDS (double-buffered). PHASE1: 1 barrier/kt. PHASE2: 1+NH/kt.
template<int PHASE>
__global__ __launch_bounds__(256, (PHASE == 1) ? 4 : 3) void attn_fused(
    const f16* __restrict__ Qp, const f16* __restrict__ Kpk,
    const f16* __restrict__ Vtt, const float* __restrict__ other,
    const unsigned char* __restrict__ mask8, const int* __restrict__ mask32,
    const unsigned int* __restrict__ flag, float* __restrict__ lsum2,
    float* __restrict__ attn_out, f16* __restrict__ ctx2) {
  constexpr int NH = (PHASE == 1) ? 8 : 4;
  __shared__ char smem_raw[(PHASE == 1) ? (2 * 16896 + 4096) : (16896 + 2 * 8704)];
  float* othm0 = (float*)smem_raw;              // [32][132]
  float* othm1 = (float*)(smem_raw + 16896);    // phase1 double buffer
  f16* Ps = (f16*)(smem_raw + 16896);           // phase2 [2][32][136]
  float* red = (float*)(smem_raw + 2 * 16896);  // phase1 [4][8][32]

  const int t = threadIdx.x;
  const int bid = blockIdx.x;
  const int b  = (bid & 7) >> 1;
  const int kh = bid & 1;
  int qblk, h0;
  if (PHASE == 1) { qblk = (bid >> 3) * 32; h0 = 0; }
  else            { h0 = ((bid >> 3) & 1) * 4; qblk = (bid >> 4) * 32; }
  const int w = t >> 6, ln = t & 63;
  const int lr = ln & 15, lg = ln >> 4;
  const int qw = w & 1, dvb = (w >> 1) * 32;
  const bool use8 = (*flag) != 0;

  float invl[NH][2];
  if (PHASE == 2) {
    #pragma unroll
    for (int hh = 0; hh < NH; hh++)
      #pragma unroll
      for (int m = 0; m < 2; m++) {
        size_t qi = (size_t)(b * 8 + h0 + hh) * SS + qblk + m * 16 + lr;
        invl[hh][m] = 1.0f / (lsum2[qi] + lsum2[(size_t)BHN * SS + qi]);
      }
  }

  float rs[NH][2];
  #pragma unroll
  for (int hh = 0; hh < NH; hh++) { rs[hh][0] = 0.f; rs[hh][1] = 0.f; }
  float4v cacc[NH][2] = {};

  for (int kt = 0; kt < 8; kt++) {
    const int kb = kh * 1024 + kt * 128;
    float* othm = (PHASE == 1 && (kt & 1)) ? othm1 : othm0;
    // ---- stage other+mask tile once per kt ----
    {
      const int q = t >> 3, k0 = (t & 7) * 16;
      const size_t base = ((size_t)b * SS + qblk + q) * SS + kb + k0;
      const float* op = other + base;
      float4v o[4];
      #pragma unroll
      for (int j = 0; j < 4; j++) o[j] = *(const float4v*)(op + j * 4);
      float* od = othm + q * 132 + k0;
      if (use8) {
        uint4v mv = *(const uint4v*)(mask8 + base);
        #pragma unroll
        for (int j = 0; j < 4; j++) {
          unsigned int mm = mv[j];
          float4v r;
          #pragma unroll
          for (int rr = 0; rr < 4; rr++)
            r[rr] = ((mm >> (8 * rr)) & 0xffu) ? -1e9f : o[j][rr] * L2E;
          *(float4v*)(od + j * 4) = r;
        }
      } else {
        #pragma unroll
        for (int j = 0; j < 4; j++) {
          int4v m4 = *(const int4v*)(mask32 + base + j * 4);
          float4v r;
          #pragma unroll
          for (int rr = 0; rr < 4; rr++)
            r[rr] = m4[rr] ? -1e9f : o[j][rr] * L2E;
          *(float4v*)(od + j * 4) = r;
        }
      }
    }
    __syncthreads();  // othm ready (phase1 dbuf; phase2 single-buf safe: all
                      // prev-kt othm reads precede the last head's Ps barrier)
    #pragma unroll
    for (int hh = 0; hh < NH; hh++) {
      const int h = h0 + hh;
      const int bh2 = b * 8 + h;
      // Q fragments (L2-hot)
      half8 qf[2][2];
      #pragma unroll
      for (int m = 0; m < 2; m++) {
        const f16* qp = Qp + ((size_t)b * SS + qblk + m * 16 + lr) * 512 + h * 64 + lg * 8;
        qf[m][0] = *(const half8*)qp;
        qf[m][1] = *(const half8*)(qp + 32);
      }
      // K fragments direct (wave-disjoint rows)
      const f16* kbase = Kpk + ((size_t)bh2 * SS + kb + w * 32 + lr) * 64 + lg * 8;
      half8 kf[2][2];
      #pragma unroll
      for (int n = 0; n < 2; n++)
        #pragma unroll
        for (int ks = 0; ks < 2; ks++)
          kf[n][ks] = *(const half8*)(kbase + n * 1024 + ks * 32);
      // QK^T transposed: A = K (rows = k token), B = Q (cols = q)
      float4v sacc[2][2] = {};  // [n (k)][m (q)]
      #pragma unroll
      for (int ks = 0; ks < 2; ks++)
        #pragma unroll
        for (int n = 0; n < 2; n++)
          #pragma unroll
          for (int m = 0; m < 2; m++)
            sacc[n][m] = mfma16(kf[n][ks], qf[m][ks], sacc[n][m]);
      // ---- epilogue: bias(from LDS) + exp (+ normalize/store) ----
      #pragma unroll
      for (int n = 0; n < 2; n++) {
        #pragma unroll
        for (int m = 0; m < 2; m++) {
          const int q_l = m * 16 + lr;
          const int kc = w * 32 + n * 16 + lg * 4;
          float4v oth = *(const float4v*)(othm + q_l * 132 + kc);
          float4v ev;
          #pragma unroll
          for (int r = 0; r < 4; r++)
            ev[r] = exp2f(fmaf(sacc[n][m][r], SCALE_L2E, oth[r]));
          if (PHASE == 1) {
            rs[hh][m] += (ev[0] + ev[1]) + (ev[2] + ev[3]);
          } else {
            float4v av = ev * invl[hh][m];
            *(float4v*)&attn_out[((size_t)bh2 * SS + qblk + q_l) * SS + kb + kc] = av;
            half4 ph;
            ph[0] = (f16)av[0]; ph[1] = (f16)av[1];
            ph[2] = (f16)av[2]; ph[3] = (f16)av[3];
            *(half4*)&Ps[((hh & 1) * 32 + q_l) * 136 + kc] = ph;
          }
        }
      }
      if (PHASE == 2) {
        // V fragments: issue before the barrier -> latency hidden by the
        // mandatory vmcnt(0) drain at the barrier.
        half8 vf[2][4];
        const f16* vbase = Vtt + ((size_t)bh2 * 64 + dvb + lr) * SS + kb + lg * 8;
        #pragma unroll
        for (int n = 0; n < 2; n++)
          #pragma unroll
          for (int ks = 0; ks < 4; ks++)
            vf[n][ks] = *(const half8*)(vbase + (size_t)n * 16 * SS + ks * 32);
        __syncthreads();  // Ps[hh&1] complete
        #pragma unroll
        for (int ks = 0; ks < 4; ks++) {
          half8 pf = *(const half8*)&Ps[((hh & 1) * 32 + qw * 16 + lr) * 136 + ks * 32 + lg * 8];
          #pragma unroll
          for (int n = 0; n < 2; n++)
            cacc[hh][n] = mfma16(pf, vf[n][ks], cacc[hh][n]);
        }
      }
    }
  }

  if (PHASE == 1) {
    #pragma unroll
    for (int hh = 0; hh < NH; hh++) {
      #pragma unroll
      for (int m = 0; m < 2; m++) {
        float v = rs[hh][m];
        v += __shfl_xor(v, 16);
        v += __shfl_xor(v, 32);
        if (ln < 16) red[(w * 8 + hh) * 32 + m * 16 + lr] = v;
      }
    }
    __syncthreads();
    {
      const int h = t >> 5, q = t & 31;
      float tot = red[(0 + h) * 32 + q] + red[(8 + h) * 32 + q] +
                  red[(16 + h) * 32 + q] + red[(24 + h) * 32 + q];
      lsum2[(size_t)kh * BHN * SS + (size_t)(b * 8 + h) * SS + qblk + q] = tot;
    }
  } else {
    #pragma unroll
    for (int hh = 0; hh < NH; hh++) {
      #pragma unroll
      for (int n = 0; n < 2; n++) {
        #pragma unroll
        for (int r = 0; r < 4; r++) {
          ctx2[(size_t)kh * MTOK * 512 +
               ((size_t)b * SS + qblk + qw * 16 + lg * 4 + r) * 512 +
               (h0 + hh) * 64 + dvb + n * 16 + lr] = (f16)cacc[hh][n][r];
        }
      }
    }
  }
}

extern "C" void kernel_launch(void* const* d_in, const int* in_sizes, int n_in,
                              void* d_out, int out_size, void* d_ws, size_t ws_size,
                              hipStream_t stream) {
  const float* inQ   = (const float*)d_in[0];
  const float* inK   = (const float*)d_in[1];
  const float* inV   = (const float*)d_in[2];
  const void*  mask  = d_in[3];
  const float* other = (const float*)d_in[4];
  const float* WQ    = (const float*)d_in[5];
  const float* WK    = (const float*)d_in[6];
  const float* WV    = (const float*)d_in[7];
  const float* WF    = (const float*)d_in[8];

  char* ws = (char*)d_ws;
  size_t off = 0;
  unsigned int* flag = (unsigned int*)(ws + off); off += 256;
  f16* Qp    = (f16*)(ws + off); off += (size_t)MTOK * 512 * 2;
  f16* Kpk   = (f16*)(ws + off); off += (size_t)MTOK * 512 * 2;
  f16* Vtt   = (f16*)(ws + off); off += (size_t)MTOK * 512 * 2;
  float* lsum2 = (float*)(ws + off); off += (size_t)2 * BHN * SS * 4;
  f16* ctx2  = (f16*)(ws + off); off += (size_t)2 * MTOK * 512 * 2;
  if (ws_size < off) return;

  float* outp  = (float*)d_out;
  float* attnp = outp + (size_t)MTOK * DDIM;

  hipMemsetAsync(flag, 0, 256, stream);
  detect_mask_kernel<<<1, 256, 0, stream>>>((const unsigned int*)mask, flag);

  gemm_qkv<<<dim3(64, 4, 3), 256, 0, stream>>>(inQ, inK, inV, WQ, WK, WV,
                                               Qp, Kpk, Vtt);

  attn_fused<1><<<512, 256, 0, stream>>>(
      Qp, Kpk, Vtt, other, (const unsigned char*)mask, (const int*)mask, flag,
      lsum2, attnp, ctx2);
  attn_fused<2><<<1024, 256, 0, stream>>>(
      Qp, Kpk, Vtt, other, (const unsigned char*)mask, (const int*)mask, flag,
      lsum2, attnp, ctx2);

  gemm_out<<<dim3(64, 4), 256, 0, stream>>>(ctx2, WF, outp);
}